// Round 7
// baseline (410.697 us; speedup 1.0000x reference)
//
// round 7: 2-pass fused attention — attn_stats (online m,l; L1 variant builds Mmask)
//          + gemm_attn (p computed in-staging, attnb eliminated)
#include <hip/hip_runtime.h>
#include <math.h>

#define NROW 4096
#define ALPHA_SLOPE 0.2f

typedef __attribute__((ext_vector_type(8))) short bf16x8;
typedef __attribute__((ext_vector_type(4))) float f32x4;

__device__ __forceinline__ ushort f2bf(float f) {
    union { float f; unsigned u; } v; v.f = f;
    unsigned r = v.u + 0x7fffu + ((v.u >> 16) & 1u);   // RNE
    return (ushort)(r >> 16);
}
__device__ __forceinline__ float bf2f(ushort u) {
    union { unsigned u; float f; } v; v.u = ((unsigned)u) << 16;
    return v.f;
}

// ================= bf16 MFMA GEMM, BK=64, both-sides-swizzled LDS =================
// C[M][N] f32 = A[M][K] bf16 row-major @ Bt[N][K] bf16 row-major (B^T input).
// Tile 128 x BN (BN = NF*32), 4 waves (2x2), BK=64, split-K via grid.z.
template<int NF>
__global__ __launch_bounds__(256)
void gemm_bf16(const ushort* __restrict__ A, const ushort* __restrict__ Bt,
               float* __restrict__ C, float* __restrict__ P,
               int M, int N, int K, int Ks)
{
    constexpr int BN  = NF * 32;
    constexpr int APT = 4;
    constexpr int BPT = BN * 8 / 256;
    __shared__ ushort As[128 * 64];
    __shared__ ushort Bs[BN * 64];
    const int tid  = threadIdx.x;
    const int lane = tid & 63;
    const int wave = tid >> 6;
    const int wr = wave >> 1, wc = wave & 1;
    const int row0 = blockIdx.y * 128;
    const int col0 = blockIdx.x * BN;
    const size_t koff = (size_t)blockIdx.z * Ks;

    f32x4 acc[4][NF];
    #pragma unroll
    for (int i = 0; i < 4; ++i)
        #pragma unroll
        for (int j = 0; j < NF; ++j) acc[i][j] = (f32x4){0.f, 0.f, 0.f, 0.f};

    const ushort* pA[APT]; int dA[APT];
    #pragma unroll
    for (int j = 0; j < APT; ++j) {
        const int s = tid + 256 * j;
        const int r = s >> 3, c = s & 7;
        pA[j] = A + (size_t)(row0 + r) * K + koff + (size_t)(c ^ (r & 7)) * 8;
        dA[j] = s * 8;
    }
    const ushort* pB[BPT]; int dB[BPT];
    #pragma unroll
    for (int j = 0; j < BPT; ++j) {
        const int s = tid + 256 * j;
        const int r = s >> 3, c = s & 7;
        const int rg = (col0 + r < N) ? (col0 + r) : (N - 1);
        pB[j] = Bt + (size_t)rg * K + koff + (size_t)(c ^ (r & 7)) * 8;
        dB[j] = s * 8;
    }

    const int arow0 = wr * 64 + (lane & 15);
    const int brow0 = wc * (BN / 2) + (lane & 15);
    const int acg   = lane >> 4;

    bf16x8 vA[APT], vB[BPT];
    #pragma unroll
    for (int j = 0; j < APT; ++j) vA[j] = *(const bf16x8*)(pA[j]);
    #pragma unroll
    for (int j = 0; j < BPT; ++j) vB[j] = *(const bf16x8*)(pB[j]);

    for (int k0 = 0; k0 < Ks; k0 += 64) {
        __syncthreads();
        #pragma unroll
        for (int j = 0; j < APT; ++j) *(bf16x8*)(As + dA[j]) = vA[j];
        #pragma unroll
        for (int j = 0; j < BPT; ++j) *(bf16x8*)(Bs + dB[j]) = vB[j];
        __syncthreads();
        if (k0 + 64 < Ks) {
            #pragma unroll
            for (int j = 0; j < APT; ++j) vA[j] = *(const bf16x8*)(pA[j] + k0 + 64);
            #pragma unroll
            for (int j = 0; j < BPT; ++j) vB[j] = *(const bf16x8*)(pB[j] + k0 + 64);
        }
        #pragma unroll
        for (int kk = 0; kk < 2; ++kk) {
            const int Q = kk * 4 + acg;
            bf16x8 af[4], bfr[NF];
            #pragma unroll
            for (int mi = 0; mi < 4; ++mi) {
                const int r = arow0 + mi * 16;
                af[mi] = *(const bf16x8*)(As + (r * 8 + (Q ^ (r & 7))) * 8);
            }
            #pragma unroll
            for (int ni = 0; ni < NF; ++ni) {
                const int r = brow0 + ni * 16;
                bfr[ni] = *(const bf16x8*)(Bs + (r * 8 + (Q ^ (r & 7))) * 8);
            }
            #pragma unroll
            for (int mi = 0; mi < 4; ++mi)
                #pragma unroll
                for (int ni = 0; ni < NF; ++ni)
                    acc[mi][ni] = __builtin_amdgcn_mfma_f32_16x16x32_bf16(
                        af[mi], bfr[ni], acc[mi][ni], 0, 0, 0);
        }
    }

    float* outp = (blockIdx.z == gridDim.z - 1) ? C : (P + (size_t)blockIdx.z * M * N);
    const int crow  = row0 + wr * 64 + (lane >> 4) * 4;
    const int ccol0 = col0 + wc * (BN / 2) + (lane & 15);
    #pragma unroll
    for (int mi = 0; mi < 4; ++mi)
        #pragma unroll
        for (int ni = 0; ni < NF; ++ni) {
            const int cc = ccol0 + ni * 16;
            if (cc < N) {
                #pragma unroll
                for (int j = 0; j < 4; ++j)
                    outp[(size_t)(crow + mi * 16 + j) * N + cc] = acc[mi][ni][j];
            }
        }
}

// ========== gemm_attn: same GEMM, but A = softmax-p computed at staging ==========
// p[i][j] = Mmask[i][j] < 0 ? 0 : exp(lrelu((es_i + en_j)*Mmask[i][j]) - mt_i)
// Mmask is [NROW][NROW] bf16 row-major, K = NROW.
template<int NF>
__global__ __launch_bounds__(256)
void gemm_attn(const ushort* __restrict__ Mmask, const float* __restrict__ es,
               const float* __restrict__ en, const float* __restrict__ mt,
               const ushort* __restrict__ Bt, float* __restrict__ C,
               float* __restrict__ P, int M, int N, int Ks)
{
    constexpr int BN  = NF * 32;
    constexpr int BPT = BN * 8 / 256;
    __shared__ ushort As[128 * 64];
    __shared__ ushort Bs[BN * 64];
    const int tid  = threadIdx.x;
    const int lane = tid & 63;
    const int wave = tid >> 6;
    const int wr = wave >> 1, wc = wave & 1;
    const int row0 = blockIdx.y * 128;
    const int col0 = blockIdx.x * BN;
    const size_t koff = (size_t)blockIdx.z * Ks;

    f32x4 acc[4][NF];
    #pragma unroll
    for (int i = 0; i < 4; ++i)
        #pragma unroll
        for (int j = 0; j < NF; ++j) acc[i][j] = (f32x4){0.f, 0.f, 0.f, 0.f};

    // A slots: per thread 4 slots; per slot: row r, swizzled source chunk
    const ushort* pM[4]; int dA[4], jb[4]; float esr[4], mtr[4];
    #pragma unroll
    for (int j = 0; j < 4; ++j) {
        const int s = tid + 256 * j;
        const int r = s >> 3, c = s & 7;
        const int cs = c ^ (r & 7);
        pM[j]  = Mmask + (size_t)(row0 + r) * NROW + koff + (size_t)cs * 8;
        jb[j]  = (int)koff + cs * 8;
        dA[j]  = s * 8;
        esr[j] = es[row0 + r];
        mtr[j] = mt[row0 + r];
    }
    const ushort* pB[BPT]; int dB[BPT];
    #pragma unroll
    for (int j = 0; j < BPT; ++j) {
        const int s = tid + 256 * j;
        const int r = s >> 3, c = s & 7;
        const int rg = (col0 + r < N) ? (col0 + r) : (N - 1);
        pB[j] = Bt + (size_t)rg * NROW + koff + (size_t)(c ^ (r & 7)) * 8;
        dB[j] = s * 8;
    }

    const int arow0 = wr * 64 + (lane & 15);
    const int brow0 = wc * (BN / 2) + (lane & 15);
    const int acg   = lane >> 4;

    bf16x8 vM[4], vB[BPT];
    #pragma unroll
    for (int j = 0; j < 4; ++j) vM[j] = *(const bf16x8*)(pM[j]);
    #pragma unroll
    for (int j = 0; j < BPT; ++j) vB[j] = *(const bf16x8*)(pB[j]);

    for (int k0 = 0; k0 < Ks; k0 += 64) {
        __syncthreads();
        #pragma unroll
        for (int j = 0; j < 4; ++j) {
            const float4 ea = *(const float4*)(en + jb[j] + k0);
            const float4 eb = *(const float4*)(en + jb[j] + k0 + 4);
            const float ev[8] = {ea.x, ea.y, ea.z, ea.w, eb.x, eb.y, eb.z, eb.w};
            ushort po[8];
            #pragma unroll
            for (int c = 0; c < 8; ++c) {
                const float mv = bf2f(((const ushort*)&vM[j])[c]);
                const float t  = (esr[j] + ev[c]) * mv;
                const float e2 = (t >= 0.f) ? t : ALPHA_SLOPE * t;
                const float p  = (mv < 0.f) ? 0.f : __expf(e2 - mtr[j]);
                po[c] = f2bf(p);
            }
            *(bf16x8*)(As + dA[j]) = *(const bf16x8*)po;
        }
        #pragma unroll
        for (int j = 0; j < BPT; ++j) *(bf16x8*)(Bs + dB[j]) = vB[j];
        __syncthreads();
        if (k0 + 64 < Ks) {
            #pragma unroll
            for (int j = 0; j < 4; ++j) vM[j] = *(const bf16x8*)(pM[j] + k0 + 64);
            #pragma unroll
            for (int j = 0; j < BPT; ++j) vB[j] = *(const bf16x8*)(pB[j] + k0 + 64);
        }
        #pragma unroll
        for (int kk = 0; kk < 2; ++kk) {
            const int Q = kk * 4 + acg;
            bf16x8 af[4], bfr[NF];
            #pragma unroll
            for (int mi = 0; mi < 4; ++mi) {
                const int r = arow0 + mi * 16;
                af[mi] = *(const bf16x8*)(As + (r * 8 + (Q ^ (r & 7))) * 8);
            }
            #pragma unroll
            for (int ni = 0; ni < NF; ++ni) {
                const int r = brow0 + ni * 16;
                bfr[ni] = *(const bf16x8*)(Bs + (r * 8 + (Q ^ (r & 7))) * 8);
            }
            #pragma unroll
            for (int mi = 0; mi < 4; ++mi)
                #pragma unroll
                for (int ni = 0; ni < NF; ++ni)
                    acc[mi][ni] = __builtin_amdgcn_mfma_f32_16x16x32_bf16(
                        af[mi], bfr[ni], acc[mi][ni], 0, 0, 0);
        }
    }

    float* outp = (blockIdx.z == gridDim.z - 1) ? C : (P + (size_t)blockIdx.z * M * N);
    const int crow  = row0 + wr * 64 + (lane >> 4) * 4;
    const int ccol0 = col0 + wc * (BN / 2) + (lane & 15);
    #pragma unroll
    for (int mi = 0; mi < 4; ++mi)
        #pragma unroll
        for (int ni = 0; ni < NF; ++ni) {
            const int cc = ccol0 + ni * 16;
            if (cc < N) {
                #pragma unroll
                for (int j = 0; j < 4; ++j)
                    outp[(size_t)(crow + mi * 16 + j) * N + cc] = acc[mi][ni][j];
            }
        }
}

// ========== attn_stats: per-row online softmax stats; mt = m + ln(l) ==========
// adj/Mm non-null (layer 1): read f32 adj,M; write Mmaskb bf16; compute stats.
// else: read Mmaskb bf16.
__global__ __launch_bounds__(256)
void attn_stats(const float4* __restrict__ adj, const float4* __restrict__ Mm,
                ushort4* __restrict__ MmW, const ushort4* __restrict__ MmR,
                const float* __restrict__ es, const float* __restrict__ en,
                float* __restrict__ mt)
{
    const int i = blockIdx.x;
    const float esi = es[i];
    const float4* E4 = (const float4*)en;
    const int tid = threadIdx.x, lane = tid & 63, w = tid >> 6;
    const size_t rb = (size_t)i * (NROW / 4);

    float m = -3.0e38f, l = 0.f;
    for (int t = tid; t < NROW / 4; t += 256) {
        float mv4[4];
        if (adj) {
            const float4 a = adj[rb + t];
            const float4 mm = Mm[rb + t];
            mv4[0] = a.x > 0.f ? mm.x : -1.f;
            mv4[1] = a.y > 0.f ? mm.y : -1.f;
            mv4[2] = a.z > 0.f ? mm.z : -1.f;
            mv4[3] = a.w > 0.f ? mm.w : -1.f;
            ushort4 o;
            o.x = f2bf(mv4[0]); o.y = f2bf(mv4[1]);
            o.z = f2bf(mv4[2]); o.w = f2bf(mv4[3]);
            MmW[rb + t] = o;
            // re-read rounded values for exact consistency with gemm_attn
            mv4[0] = bf2f(o.x); mv4[1] = bf2f(o.y);
            mv4[2] = bf2f(o.z); mv4[3] = bf2f(o.w);
        } else {
            const ushort4 mq = MmR[rb + t];
            mv4[0] = bf2f(mq.x); mv4[1] = bf2f(mq.y);
            mv4[2] = bf2f(mq.z); mv4[3] = bf2f(mq.w);
        }
        const float4 e4 = E4[t];
        const float ev[4] = {e4.x, e4.y, e4.z, e4.w};
        #pragma unroll
        for (int c = 0; c < 4; ++c) {
            const float mv = mv4[c];
            if (mv >= 0.f) {
                const float tt = (esi + ev[c]) * mv;
                const float e = (tt >= 0.f) ? tt : ALPHA_SLOPE * tt;
                if (e > m) { l = l * __expf(m - e) + 1.f; m = e; }
                else l += __expf(e - m);
            }
        }
    }
    // merge (m,l) across 64 lanes
    #pragma unroll
    for (int off = 32; off; off >>= 1) {
        const float mo = __shfl_xor(m, off);
        const float lo = __shfl_xor(l, off);
        const float mn = fmaxf(m, mo);
        const float t1 = (m  <= -1.0e38f) ? 0.f : l  * __expf(m  - mn);
        const float t2 = (mo <= -1.0e38f) ? 0.f : lo * __expf(mo - mn);
        m = mn; l = t1 + t2;
    }
    __shared__ float sm[4], sl[4];
    if (lane == 0) { sm[w] = m; sl[w] = l; }
    __syncthreads();
    if (tid == 0) {
        float M2 = fmaxf(fmaxf(sm[0], sm[1]), fmaxf(sm[2], sm[3]));
        float L2 = 0.f;
        #pragma unroll
        for (int q = 0; q < 4; ++q)
            L2 += (sm[q] <= -1.0e38f) ? 0.f : sl[q] * __expf(sm[q] - M2);
        mt[i] = M2 + logf(L2);
    }
}

// C[i] += sum_{s<nm1} P[s][i]  (fixed order — deterministic)
__global__ void reduce_k(float4* __restrict__ C, const float4* __restrict__ P,
                         int nm1, int n4)
{
    for (int i = blockIdx.x * 256 + threadIdx.x; i < n4; i += gridDim.x * 256) {
        float4 c = C[i];
        for (int s = 0; s < nm1; ++s) {
            const float4 p = P[(size_t)s * n4 + i];
            c.x += p.x; c.y += p.y; c.z += p.z; c.w += p.w;
        }
        C[i] = c;
    }
}

// ================= f32 GEMM (tiny z1 gemm only) =================
__global__ __launch_bounds__(256)
void gemm_f32(const float* __restrict__ A, const float* __restrict__ B,
              float* __restrict__ C, int M, int Nc, int K)
{
    __shared__ float As[16][65];
    __shared__ float Bs[16][65];
    const int tid = threadIdx.x;
    const int tr = tid >> 4;
    const int tc = tid & 15;
    const int row0 = blockIdx.y * 64;
    const int col0 = blockIdx.x * 64;
    float acc[4][4] = {{0.f}};

    for (int k0 = 0; k0 < K; k0 += 16) {
        {
            const int r  = tid >> 2;
            const int c4 = (tid & 3) * 4;
            const float* ap = A + (size_t)(row0 + r) * K + k0 + c4;
            const float4 v = *reinterpret_cast<const float4*>(ap);
            As[c4 + 0][r] = v.x; As[c4 + 1][r] = v.y;
            As[c4 + 2][r] = v.z; As[c4 + 3][r] = v.w;
        }
        {
            const int kk = tid >> 4;
            const int c4 = (tid & 15) * 4;
            const float* bp = B + (size_t)(k0 + kk) * Nc + col0 + c4;
            float4 v;
            if (col0 + c4 + 3 < Nc) {
                v = *reinterpret_cast<const float4*>(bp);
            } else {
                v.x = (col0 + c4 + 0 < Nc) ? bp[0] : 0.f;
                v.y = (col0 + c4 + 1 < Nc) ? bp[1] : 0.f;
                v.z = (col0 + c4 + 2 < Nc) ? bp[2] : 0.f;
                v.w = (col0 + c4 + 3 < Nc) ? bp[3] : 0.f;
            }
            Bs[kk][c4 + 0] = v.x; Bs[kk][c4 + 1] = v.y;
            Bs[kk][c4 + 2] = v.z; Bs[kk][c4 + 3] = v.w;
        }
        __syncthreads();
        #pragma unroll
        for (int k = 0; k < 16; ++k) {
            float a0 = As[k][tr*4+0], a1 = As[k][tr*4+1], a2 = As[k][tr*4+2], a3 = As[k][tr*4+3];
            float b0 = Bs[k][tc*4+0], b1 = Bs[k][tc*4+1], b2 = Bs[k][tc*4+2], b3 = Bs[k][tc*4+3];
            acc[0][0]+=a0*b0; acc[0][1]+=a0*b1; acc[0][2]+=a0*b2; acc[0][3]+=a0*b3;
            acc[1][0]+=a1*b0; acc[1][1]+=a1*b1; acc[1][2]+=a1*b2; acc[1][3]+=a1*b3;
            acc[2][0]+=a2*b0; acc[2][1]+=a2*b1; acc[2][2]+=a2*b2; acc[2][3]+=a2*b3;
            acc[3][0]+=a3*b0; acc[3][1]+=a3*b1; acc[3][2]+=a3*b2; acc[3][3]+=a3*b3;
        }
        __syncthreads();
    }
    #pragma unroll
    for (int i = 0; i < 4; ++i) {
        const int r = row0 + tr * 4 + i;
        #pragma unroll
        for (int j = 0; j < 4; ++j) {
            const int c = col0 + tc * 4 + j;
            if (c < Nc) C[(size_t)r * Nc + c] = acc[i][j];
        }
    }
}

// ================= transpose f32 [R][C] -> bf16 [C][R] =================
__global__ __launch_bounds__(256)
void transpose_bf16(const float* __restrict__ in, ushort* __restrict__ out, int R, int C)
{
    __shared__ float t[32][33];
    const int r0 = blockIdx.y * 32, c0 = blockIdx.x * 32;
    const int j = threadIdx.x & 31;
    for (int i = threadIdx.x >> 5; i < 32; i += 8)
        if (r0 + i < R && c0 + j < C)
            t[i][j] = in[(size_t)(r0 + i) * C + c0 + j];
    __syncthreads();
    for (int i = threadIdx.x >> 5; i < 32; i += 8)
        if (c0 + i < C && r0 + j < R)
            out[(size_t)(c0 + i) * R + r0 + j] = f2bf(t[j][i]);
}

// ================= f32 -> bf16 convert =================
__global__ void conv_bf16(const float4* __restrict__ in, ushort4* __restrict__ out, int n4)
{
    for (int i = blockIdx.x * 256 + threadIdx.x; i < n4; i += gridDim.x * 256) {
        const float4 v = in[i];
        ushort4 o;
        o.x = f2bf(v.x); o.y = f2bf(v.y); o.z = f2bf(v.z); o.w = f2bf(v.w);
        out[i] = o;
    }
}

// ================= per-row dots =================
__global__ __launch_bounds__(256)
void scores_kernel(const float* __restrict__ h, const float* __restrict__ a_self,
                   const float* __restrict__ a_neigh, float* __restrict__ es,
                   float* __restrict__ en, int d)
{
    const int i = blockIdx.x;
    const float* hr = h + (size_t)i * d;
    float ps = 0.f, pn = 0.f;
    for (int k = threadIdx.x; k < d; k += 256) {
        const float hv = hr[k];
        ps += hv * a_self[k];
        pn += hv * a_neigh[k];
    }
    #pragma unroll
    for (int off = 32; off; off >>= 1) {
        ps += __shfl_down(ps, off);
        pn += __shfl_down(pn, off);
    }
    __shared__ float ss[4], sn[4];
    const int lane = threadIdx.x & 63, w = threadIdx.x >> 6;
    if (lane == 0) { ss[w] = ps; sn[w] = pn; }
    __syncthreads();
    if (threadIdx.x == 0) {
        es[i] = ss[0] + ss[1] + ss[2] + ss[3];
        en[i] = sn[0] + sn[1] + sn[2] + sn[3];
    }
}

// ================= elu + optional mix =================
__global__ void elu_mix(const float4* __restrict__ hp, const float4* __restrict__ enc,
                        ushort4* __restrict__ outb, float4* __restrict__ outf, int n4)
{
    for (int i = blockIdx.x * 256 + threadIdx.x; i < n4; i += gridDim.x * 256) {
        const float4 v = hp[i];
        float4 h;
        h.x = (v.x > 0.f) ? v.x : expm1f(v.x);
        h.y = (v.y > 0.f) ? v.y : expm1f(v.y);
        h.z = (v.z > 0.f) ? v.z : expm1f(v.z);
        h.w = (v.w > 0.f) ? v.w : expm1f(v.w);
        if (outf) outf[i] = h;
        if (outb) {
            const float4 e = enc[i];
            ushort4 o;
            o.x = f2bf(0.6f * h.x + 0.4f * e.x);
            o.y = f2bf(0.6f * h.y + 0.4f * e.y);
            o.z = f2bf(0.6f * h.z + 0.4f * e.z);
            o.w = f2bf(0.6f * h.w + 0.4f * e.w);
            outb[i] = o;
        }
    }
}

// ================= tmat[512][16] = h1^T @ h4 =================
__global__ __launch_bounds__(256)
void ata_kernel(const float* __restrict__ h1, const float* __restrict__ h4,
                float* __restrict__ tmat)
{
    const int r = blockIdx.x;
    float acc[16];
    #pragma unroll
    for (int c = 0; c < 16; ++c) acc[c] = 0.f;
    for (int n = threadIdx.x; n < NROW; n += 256) {
        const float hv = h1[(size_t)n * 512 + r];
        const float* h4r = h4 + (size_t)n * 16;
        #pragma unroll
        for (int c = 0; c < 16; ++c) acc[c] += hv * h4r[c];
    }
    #pragma unroll
    for (int c = 0; c < 16; ++c)
        #pragma unroll
        for (int off = 32; off; off >>= 1) acc[c] += __shfl_down(acc[c], off);
    __shared__ float red[4][16];
    const int lane = threadIdx.x & 63, w = threadIdx.x >> 6;
    if (lane == 0)
        for (int c = 0; c < 16; ++c) red[w][c] = acc[c];
    __syncthreads();
    if (threadIdx.x < 16)
        tmat[r * 16 + threadIdx.x] = red[0][threadIdx.x] + red[1][threadIdx.x] +
                                     red[2][threadIdx.x] + red[3][threadIdx.x];
}

// ================= row L2 normalize =================
__global__ __launch_bounds__(64)
void norm_kernel(const float* __restrict__ z1, float* __restrict__ out)
{
    const int i = blockIdx.x;
    const int lane = threadIdx.x;
    const float v = (lane < 16) ? z1[(size_t)i * 16 + lane] : 0.f;
    float sq = v * v;
    #pragma unroll
    for (int off = 32; off; off >>= 1) sq += __shfl_down(sq, off);
    const float tot = __shfl(sq, 0);
    const float inv = 1.0f / fmaxf(sqrtf(tot), 1e-12f);
    if (lane < 16) out[(size_t)i * 16 + lane] = v * inv;
}

extern "C" void kernel_launch(void* const* d_in, const int* in_sizes, int n_in,
                              void* d_out, int out_size, void* d_ws, size_t ws_size,
                              hipStream_t stream)
{
    const float* x    = (const float*)d_in[0];
    const float* adj  = (const float*)d_in[1];
    const float* Mm   = (const float*)d_in[2];
    const float* enc1 = (const float*)d_in[3];
    const float* enc2 = (const float*)d_in[4];
    const float* emb  = (const float*)d_in[5];
    const float* W1  = (const float*)d_in[6];
    const float* as1 = (const float*)d_in[7];
    const float* an1 = (const float*)d_in[8];
    const float* W2  = (const float*)d_in[9];
    const float* as2 = (const float*)d_in[10];
    const float* an2 = (const float*)d_in[11];
    const float* W3  = (const float*)d_in[12];
    const float* as3 = (const float*)d_in[13];
    const float* an3 = (const float*)d_in[14];
    const float* W4  = (const float*)d_in[15];
    const float* as4 = (const float*)d_in[16];
    const float* an4 = (const float*)d_in[17];
    float* out = (float*)d_out;
    (void)in_sizes; (void)n_in; (void)out_size;

    char* ws = (char*)d_ws;
    size_t off = 0;
    auto alloc = [&](size_t bytes) { char* p = ws + off; off += (bytes + 255) & ~(size_t)255; return p; };

    ushort* Mmaskb = (ushort*)alloc((size_t)NROW * NROW * 2);   // 33.5 MB
    ushort* xb     = (ushort*)alloc((size_t)NROW * 1024 * 2);   // 8.4 MB
    float*  hW     = (float*) alloc((size_t)NROW * 512 * 4);    // 8.4 MB
    ushort* hWT    = (ushort*)alloc((size_t)512 * NROW * 2);    // 4.2 MB
    float*  h1     = (float*) alloc((size_t)NROW * 512 * 4);    // 8.4 MB
    ushort* inb    = (ushort*)alloc((size_t)NROW * 512 * 2);    // 4.2 MB
    float*  h4     = (float*) alloc((size_t)NROW * 16 * 4);
    ushort* W1t    = (ushort*)alloc((size_t)512 * 1024 * 2);
    ushort* W2t    = (ushort*)alloc((size_t)256 * 512 * 2);
    ushort* W3t    = (ushort*)alloc((size_t)64 * 256 * 2);
    ushort* W4t    = (ushort*)alloc((size_t)16 * 64 * 2);
    float*  es     = (float*) alloc(NROW * 4);
    float*  en     = (float*) alloc(NROW * 4);
    float*  mt     = (float*) alloc(NROW * 4);
    float*  tmat   = (float*) alloc(512 * 16 * 4);
    float*  z1     = (float*) alloc((size_t)NROW * 16 * 4);
    const size_t pbig = (size_t)3 * NROW * 512 * 4;             // 25.2 MB
    const size_t psml = (size_t)1 * NROW * 512 * 4;             // 8.4 MB
    const bool bigws = ws_size >= off + pbig + (4u << 20);
    float* Pbuf = (float*)alloc(bigws ? pbig : psml);

    auto gemmb = [&](const ushort* A, const ushort* Bt, float* C,
                     int M, int N, int K, int splits) {
        const int Ks = K / splits;
        if (N >= 128) {
            dim3 grid(N / 128, M / 128, splits);
            gemm_bf16<4><<<grid, 256, 0, stream>>>(A, Bt, C, Pbuf, M, N, K, Ks);
        } else {
            dim3 grid(1, M / 128, splits);
            gemm_bf16<2><<<grid, 256, 0, stream>>>(A, Bt, C, Pbuf, M, N, K, Ks);
        }
        if (splits > 1) {
            const int n4 = M * N / 4;
            reduce_k<<<2048, 256, 0, stream>>>((float4*)C, (const float4*)Pbuf,
                                               splits - 1, n4);
        }
    };
    auto gemma = [&](float* C, int N, int splits) {
        const int Ks = NROW / splits;
        if (N >= 128) {
            dim3 grid(N / 128, NROW / 128, splits);
            gemm_attn<4><<<grid, 256, 0, stream>>>(Mmaskb, es, en, mt, hWT, C,
                                                   Pbuf, NROW, N, Ks);
        } else {
            dim3 grid(1, NROW / 128, splits);
            gemm_attn<2><<<grid, 256, 0, stream>>>(Mmaskb, es, en, mt, hWT, C,
                                                   Pbuf, NROW, N, Ks);
        }
        if (splits > 1) {
            const int n4 = NROW * N / 4;
            reduce_k<<<2048, 256, 0, stream>>>((float4*)C, (const float4*)Pbuf,
                                               splits - 1, n4);
        }
    };
    auto trans = [&](const float* in, ushort* o, int R, int C) {
        dim3 grid((C + 31) / 32, (R + 31) / 32);
        transpose_bf16<<<grid, 256, 0, stream>>>(in, o, R, C);
    };

    const int s_att1 = bigws ? 4 : 2;
    const int s_att2 = bigws ? 4 : 2;

    // ---- one-time prep
    conv_bf16<<<2048, 256, 0, stream>>>((const float4*)x, (ushort4*)xb, NROW * 1024 / 4);
    trans(W1, W1t, 1024, 512);
    trans(W2, W2t, 512, 256);
    trans(W3, W3t, 256, 64);
    trans(W4, W4t, 64, 16);

    // ---- layer 1: [4096,1024] -> [4096,512]
    gemmb(xb, W1t, hW, NROW, 512, 1024, 2);
    scores_kernel<<<NROW, 256, 0, stream>>>(hW, as1, an1, es, en, 512);
    trans(hW, hWT, NROW, 512);
    attn_stats<<<NROW, 256, 0, stream>>>((const float4*)adj, (const float4*)Mm,
                                         (ushort4*)Mmaskb, (const ushort4*)nullptr,
                                         es, en, mt);
    gemma(hW, 512, s_att1);
    elu_mix<<<2048, 256, 0, stream>>>((const float4*)hW, (const float4*)enc1,
                                      (ushort4*)inb, (float4*)h1, NROW * 512 / 4);

    // ---- layer 2: [4096,512] -> [4096,256]
    gemmb(inb, W2t, hW, NROW, 256, 512, bigws ? 4 : 2);
    scores_kernel<<<NROW, 256, 0, stream>>>(hW, as2, an2, es, en, 256);
    trans(hW, hWT, NROW, 256);
    attn_stats<<<NROW, 256, 0, stream>>>((const float4*)nullptr, (const float4*)nullptr,
                                         (ushort4*)nullptr, (const ushort4*)Mmaskb,
                                         es, en, mt);
    gemma(hW, 256, s_att2);
    elu_mix<<<1024, 256, 0, stream>>>((const float4*)hW, (const float4*)enc2,
                                      (ushort4*)inb, (float4*)nullptr, NROW * 256 / 4);

    // ---- layer 3: [4096,256] -> [4096,64]
    gemmb(inb, W3t, hW, NROW, 64, 256, 4);
    scores_kernel<<<NROW, 256, 0, stream>>>(hW, as3, an3, es, en, 64);
    trans(hW, hWT, NROW, 64);
    attn_stats<<<NROW, 256, 0, stream>>>((const float4*)nullptr, (const float4*)nullptr,
                                         (ushort4*)nullptr, (const ushort4*)Mmaskb,
                                         es, en, mt);
    gemma(hW, 64, 8);
    elu_mix<<<512, 256, 0, stream>>>((const float4*)hW, (const float4*)emb,
                                     (ushort4*)inb, (float4*)nullptr, NROW * 64 / 4);

    // ---- layer 4: [4096,64] -> [4096,16]
    gemmb(inb, W4t, hW, NROW, 16, 64, 1);
    scores_kernel<<<NROW, 256, 0, stream>>>(hW, as4, an4, es, en, 16);
    trans(hW, hWT, NROW, 16);
    attn_stats<<<NROW, 256, 0, stream>>>((const float4*)nullptr, (const float4*)nullptr,
                                         (ushort4*)nullptr, (const ushort4*)Mmaskb,
                                         es, en, mt);
    gemma(hW, 16, 8);
    elu_mix<<<256, 256, 0, stream>>>((const float4*)hW, (const float4*)nullptr,
                                     (ushort4*)nullptr, (float4*)h4, NROW * 16 / 4);

    // ---- z1 = h1 @ (h1^T @ h4); z = rownorm(z1)
    ata_kernel<<<512, 256, 0, stream>>>(h1, h4, tmat);
    {
        dim3 grid((16 + 63) / 64, NROW / 64);
        gemm_f32<<<grid, 256, 0, stream>>>(h1, tmat, z1, NROW, 16, 512);
    }
    norm_kernel<<<NROW, 64, 0, stream>>>(z1, out);
}

// Round 8
// 336.082 us; speedup vs baseline: 1.2220x; 1.2220x over previous
//
// round 8: r6 pipeline + mmask folded into attn_build(L1) + fused finish_layer epilogue
#include <hip/hip_runtime.h>
#include <math.h>

#define NROW 4096
#define ALPHA_SLOPE 0.2f

typedef __attribute__((ext_vector_type(8))) short bf16x8;
typedef __attribute__((ext_vector_type(4))) float f32x4;

__device__ __forceinline__ ushort f2bf(float f) {
    union { float f; unsigned u; } v; v.f = f;
    unsigned r = v.u + 0x7fffu + ((v.u >> 16) & 1u);   // RNE
    return (ushort)(r >> 16);
}
__device__ __forceinline__ float bf2f(ushort u) {
    union { unsigned u; float f; } v; v.u = ((unsigned)u) << 16;
    return v.f;
}

// ================= bf16 MFMA GEMM, BK=64, both-sides-swizzled LDS =================
// C[M][N] f32 = A[M][K] bf16 row-major @ Bt[N][K] bf16 row-major (B^T input).
// Tile 128 x BN (BN = NF*32), 4 waves (2x2), BK=64, split-K via grid.z.
// Last split writes C, others write P + z*M*N.
template<int NF>
__global__ __launch_bounds__(256)
void gemm_bf16(const ushort* __restrict__ A, const ushort* __restrict__ Bt,
               float* __restrict__ C, float* __restrict__ P,
               int M, int N, int K, int Ks)
{
    constexpr int BN  = NF * 32;
    constexpr int APT = 4;
    constexpr int BPT = BN * 8 / 256;
    __shared__ ushort As[128 * 64];
    __shared__ ushort Bs[BN * 64];
    const int tid  = threadIdx.x;
    const int lane = tid & 63;
    const int wave = tid >> 6;
    const int wr = wave >> 1, wc = wave & 1;
    const int row0 = blockIdx.y * 128;
    const int col0 = blockIdx.x * BN;
    const size_t koff = (size_t)blockIdx.z * Ks;

    f32x4 acc[4][NF];
    #pragma unroll
    for (int i = 0; i < 4; ++i)
        #pragma unroll
        for (int j = 0; j < NF; ++j) acc[i][j] = (f32x4){0.f, 0.f, 0.f, 0.f};

    const ushort* pA[APT]; int dA[APT];
    #pragma unroll
    for (int j = 0; j < APT; ++j) {
        const int s = tid + 256 * j;
        const int r = s >> 3, c = s & 7;
        pA[j] = A + (size_t)(row0 + r) * K + koff + (size_t)(c ^ (r & 7)) * 8;
        dA[j] = s * 8;
    }
    const ushort* pB[BPT]; int dB[BPT];
    #pragma unroll
    for (int j = 0; j < BPT; ++j) {
        const int s = tid + 256 * j;
        const int r = s >> 3, c = s & 7;
        const int rg = (col0 + r < N) ? (col0 + r) : (N - 1);
        pB[j] = Bt + (size_t)rg * K + koff + (size_t)(c ^ (r & 7)) * 8;
        dB[j] = s * 8;
    }

    const int arow0 = wr * 64 + (lane & 15);
    const int brow0 = wc * (BN / 2) + (lane & 15);
    const int acg   = lane >> 4;

    bf16x8 vA[APT], vB[BPT];
    #pragma unroll
    for (int j = 0; j < APT; ++j) vA[j] = *(const bf16x8*)(pA[j]);
    #pragma unroll
    for (int j = 0; j < BPT; ++j) vB[j] = *(const bf16x8*)(pB[j]);

    for (int k0 = 0; k0 < Ks; k0 += 64) {
        __syncthreads();
        #pragma unroll
        for (int j = 0; j < APT; ++j) *(bf16x8*)(As + dA[j]) = vA[j];
        #pragma unroll
        for (int j = 0; j < BPT; ++j) *(bf16x8*)(Bs + dB[j]) = vB[j];
        __syncthreads();
        if (k0 + 64 < Ks) {
            #pragma unroll
            for (int j = 0; j < APT; ++j) vA[j] = *(const bf16x8*)(pA[j] + k0 + 64);
            #pragma unroll
            for (int j = 0; j < BPT; ++j) vB[j] = *(const bf16x8*)(pB[j] + k0 + 64);
        }
        #pragma unroll
        for (int kk = 0; kk < 2; ++kk) {
            const int Q = kk * 4 + acg;
            bf16x8 af[4], bfr[NF];
            #pragma unroll
            for (int mi = 0; mi < 4; ++mi) {
                const int r = arow0 + mi * 16;
                af[mi] = *(const bf16x8*)(As + (r * 8 + (Q ^ (r & 7))) * 8);
            }
            #pragma unroll
            for (int ni = 0; ni < NF; ++ni) {
                const int r = brow0 + ni * 16;
                bfr[ni] = *(const bf16x8*)(Bs + (r * 8 + (Q ^ (r & 7))) * 8);
            }
            #pragma unroll
            for (int mi = 0; mi < 4; ++mi)
                #pragma unroll
                for (int ni = 0; ni < NF; ++ni)
                    acc[mi][ni] = __builtin_amdgcn_mfma_f32_16x16x32_bf16(
                        af[mi], bfr[ni], acc[mi][ni], 0, 0, 0);
        }
    }

    float* outp = (blockIdx.z == gridDim.z - 1) ? C : (P + (size_t)blockIdx.z * M * N);
    const int crow  = row0 + wr * 64 + (lane >> 4) * 4;
    const int ccol0 = col0 + wc * (BN / 2) + (lane & 15);
    #pragma unroll
    for (int mi = 0; mi < 4; ++mi)
        #pragma unroll
        for (int ni = 0; ni < NF; ++ni) {
            const int cc = ccol0 + ni * 16;
            if (cc < N) {
                #pragma unroll
                for (int j = 0; j < 4; ++j)
                    outp[(size_t)(crow + mi * 16 + j) * N + cc] = acc[mi][ni][j];
            }
        }
}

// C[i] += sum_{s<nm1} P[s][i]  (fixed order — deterministic)
__global__ void reduce_k(float4* __restrict__ C, const float4* __restrict__ P,
                         int nm1, int n4)
{
    for (int i = blockIdx.x * 256 + threadIdx.x; i < n4; i += gridDim.x * 256) {
        float4 c = C[i];
        for (int s = 0; s < nm1; ++s) {
            const float4 p = P[(size_t)s * n4 + i];
            c.x += p.x; c.y += p.y; c.z += p.z; c.w += p.w;
        }
        C[i] = c;
    }
}

// ===== finish_layer: sum split-K partials, ELU, optional mix -> bf16 / f32 =====
// s = C[i] + sum P[t][i]; h = elu(s); outf=h (f32); outb=bf16(0.6h+0.4enc)
__global__ void finish_layer(const float4* __restrict__ C, const float4* __restrict__ P,
                             int nm1, int n4, const float4* __restrict__ enc,
                             ushort4* __restrict__ outb, float4* __restrict__ outf)
{
    for (int i = blockIdx.x * 256 + threadIdx.x; i < n4; i += gridDim.x * 256) {
        float4 s = C[i];
        for (int t = 0; t < nm1; ++t) {
            const float4 p = P[(size_t)t * n4 + i];
            s.x += p.x; s.y += p.y; s.z += p.z; s.w += p.w;
        }
        float4 h;
        h.x = (s.x > 0.f) ? s.x : expm1f(s.x);
        h.y = (s.y > 0.f) ? s.y : expm1f(s.y);
        h.z = (s.z > 0.f) ? s.z : expm1f(s.z);
        h.w = (s.w > 0.f) ? s.w : expm1f(s.w);
        if (outf) outf[i] = h;
        if (outb) {
            const float4 e = enc[i];
            ushort4 o;
            o.x = f2bf(0.6f * h.x + 0.4f * e.x);
            o.y = f2bf(0.6f * h.y + 0.4f * e.y);
            o.z = f2bf(0.6f * h.z + 0.4f * e.z);
            o.w = f2bf(0.6f * h.w + 0.4f * e.w);
            outb[i] = o;
        }
    }
}

// ===== attn_build: one row per block. Masked lrelu(e*M), softmax -> bf16 attnb.
// L1 (adj != null): reads f32 adj+M, also writes Mmaskb bf16.
// L2-4 (adj == null): reads Mmaskb bf16.
__global__ __launch_bounds__(256)
void attn_build(const float4* __restrict__ adj, const float4* __restrict__ Mm,
                ushort4* __restrict__ MmW, const ushort4* __restrict__ MmR,
                const float* __restrict__ es, const float* __restrict__ en,
                ushort* __restrict__ attnb)
{
    __shared__ float p[NROW];
    __shared__ float red[4];
    const int i = blockIdx.x;
    const float esi = es[i];
    const float4* E4 = (const float4*)en;
    const int tid = threadIdx.x, lane = tid & 63, w = tid >> 6;
    const size_t rb = (size_t)i * (NROW / 4);

    float lmax = -3.0e38f;
    for (int t = tid; t < NROW / 4; t += 256) {
        float mv4[4];
        if (adj) {
            const float4 a  = adj[rb + t];
            const float4 mm = Mm[rb + t];
            ushort4 o;
            o.x = f2bf(a.x > 0.f ? mm.x : -1.f);
            o.y = f2bf(a.y > 0.f ? mm.y : -1.f);
            o.z = f2bf(a.z > 0.f ? mm.z : -1.f);
            o.w = f2bf(a.w > 0.f ? mm.w : -1.f);
            MmW[rb + t] = o;
            mv4[0] = bf2f(o.x); mv4[1] = bf2f(o.y);
            mv4[2] = bf2f(o.z); mv4[3] = bf2f(o.w);
        } else {
            const ushort4 mq = MmR[rb + t];
            mv4[0] = bf2f(mq.x); mv4[1] = bf2f(mq.y);
            mv4[2] = bf2f(mq.z); mv4[3] = bf2f(mq.w);
        }
        const float4 e4 = E4[t];
        const float ev[4] = {e4.x, e4.y, e4.z, e4.w};
        #pragma unroll
        for (int c = 0; c < 4; ++c) {
            const float mv = mv4[c];
            float e;
            if (mv < 0.f) e = -3.0e38f;
            else {
                const float tt = (esi + ev[c]) * mv;
                e = (tt >= 0.f) ? tt : ALPHA_SLOPE * tt;
            }
            p[t * 4 + c] = e;
            lmax = fmaxf(lmax, e);
        }
    }
    #pragma unroll
    for (int off = 32; off; off >>= 1) lmax = fmaxf(lmax, __shfl_down(lmax, off));
    if (lane == 0) red[w] = lmax;
    __syncthreads();
    const float m = fmaxf(fmaxf(red[0], red[1]), fmaxf(red[2], red[3]));
    __syncthreads();

    float lsum = 0.f;
    for (int t = tid; t < NROW; t += 256) {
        const float e = p[t];
        const float pe = (e <= -1.0e38f) ? 0.f : __expf(e - m);
        p[t] = pe;
        lsum += pe;
    }
    #pragma unroll
    for (int off = 32; off; off >>= 1) lsum += __shfl_down(lsum, off);
    __syncthreads();
    if (lane == 0) red[w] = lsum;
    __syncthreads();
    const float inv = 1.0f / (red[0] + red[1] + red[2] + red[3]);
    ushort4* Ar = (ushort4*)(attnb + (size_t)i * NROW);
    for (int t = tid; t < NROW / 4; t += 256) {
        ushort4 o;
        o.x = f2bf(p[t*4+0] * inv);
        o.y = f2bf(p[t*4+1] * inv);
        o.z = f2bf(p[t*4+2] * inv);
        o.w = f2bf(p[t*4+3] * inv);
        Ar[t] = o;
    }
}

// ================= f32 GEMM (tiny z1 gemm only) =================
__global__ __launch_bounds__(256)
void gemm_f32(const float* __restrict__ A, const float* __restrict__ B,
              float* __restrict__ C, int M, int Nc, int K)
{
    __shared__ float As[16][65];
    __shared__ float Bs[16][65];
    const int tid = threadIdx.x;
    const int tr = tid >> 4;
    const int tc = tid & 15;
    const int row0 = blockIdx.y * 64;
    const int col0 = blockIdx.x * 64;
    float acc[4][4] = {{0.f}};

    for (int k0 = 0; k0 < K; k0 += 16) {
        {
            const int r  = tid >> 2;
            const int c4 = (tid & 3) * 4;
            const float* ap = A + (size_t)(row0 + r) * K + k0 + c4;
            const float4 v = *reinterpret_cast<const float4*>(ap);
            As[c4 + 0][r] = v.x; As[c4 + 1][r] = v.y;
            As[c4 + 2][r] = v.z; As[c4 + 3][r] = v.w;
        }
        {
            const int kk = tid >> 4;
            const int c4 = (tid & 15) * 4;
            const float* bp = B + (size_t)(k0 + kk) * Nc + col0 + c4;
            float4 v;
            if (col0 + c4 + 3 < Nc) {
                v = *reinterpret_cast<const float4*>(bp);
            } else {
                v.x = (col0 + c4 + 0 < Nc) ? bp[0] : 0.f;
                v.y = (col0 + c4 + 1 < Nc) ? bp[1] : 0.f;
                v.z = (col0 + c4 + 2 < Nc) ? bp[2] : 0.f;
                v.w = (col0 + c4 + 3 < Nc) ? bp[3] : 0.f;
            }
            Bs[kk][c4 + 0] = v.x; Bs[kk][c4 + 1] = v.y;
            Bs[kk][c4 + 2] = v.z; Bs[kk][c4 + 3] = v.w;
        }
        __syncthreads();
        #pragma unroll
        for (int k = 0; k < 16; ++k) {
            float a0 = As[k][tr*4+0], a1 = As[k][tr*4+1], a2 = As[k][tr*4+2], a3 = As[k][tr*4+3];
            float b0 = Bs[k][tc*4+0], b1 = Bs[k][tc*4+1], b2 = Bs[k][tc*4+2], b3 = Bs[k][tc*4+3];
            acc[0][0]+=a0*b0; acc[0][1]+=a0*b1; acc[0][2]+=a0*b2; acc[0][3]+=a0*b3;
            acc[1][0]+=a1*b0; acc[1][1]+=a1*b1; acc[1][2]+=a1*b2; acc[1][3]+=a1*b3;
            acc[2][0]+=a2*b0; acc[2][1]+=a2*b1; acc[2][2]+=a2*b2; acc[2][3]+=a2*b3;
            acc[3][0]+=a3*b0; acc[3][1]+=a3*b1; acc[3][2]+=a3*b2; acc[3][3]+=a3*b3;
        }
        __syncthreads();
    }
    #pragma unroll
    for (int i = 0; i < 4; ++i) {
        const int r = row0 + tr * 4 + i;
        #pragma unroll
        for (int j = 0; j < 4; ++j) {
            const int c = col0 + tc * 4 + j;
            if (c < Nc) C[(size_t)r * Nc + c] = acc[i][j];
        }
    }
}

// ================= transpose f32 [R][C] -> bf16 [C][R] =================
__global__ __launch_bounds__(256)
void transpose_bf16(const float* __restrict__ in, ushort* __restrict__ out, int R, int C)
{
    __shared__ float t[32][33];
    const int r0 = blockIdx.y * 32, c0 = blockIdx.x * 32;
    const int j = threadIdx.x & 31;
    for (int i = threadIdx.x >> 5; i < 32; i += 8)
        if (r0 + i < R && c0 + j < C)
            t[i][j] = in[(size_t)(r0 + i) * C + c0 + j];
    __syncthreads();
    for (int i = threadIdx.x >> 5; i < 32; i += 8)
        if (c0 + i < C && r0 + j < R)
            out[(size_t)(c0 + i) * R + r0 + j] = f2bf(t[j][i]);
}

// ================= f32 -> bf16 convert =================
__global__ void conv_bf16(const float4* __restrict__ in, ushort4* __restrict__ out, int n4)
{
    for (int i = blockIdx.x * 256 + threadIdx.x; i < n4; i += gridDim.x * 256) {
        const float4 v = in[i];
        ushort4 o;
        o.x = f2bf(v.x); o.y = f2bf(v.y); o.z = f2bf(v.z); o.w = f2bf(v.w);
        out[i] = o;
    }
}

// ================= per-row dots =================
__global__ __launch_bounds__(256)
void scores_kernel(const float* __restrict__ h, const float* __restrict__ a_self,
                   const float* __restrict__ a_neigh, float* __restrict__ es,
                   float* __restrict__ en, int d)
{
    const int i = blockIdx.x;
    const float* hr = h + (size_t)i * d;
    float ps = 0.f, pn = 0.f;
    for (int k = threadIdx.x; k < d; k += 256) {
        const float hv = hr[k];
        ps += hv * a_self[k];
        pn += hv * a_neigh[k];
    }
    #pragma unroll
    for (int off = 32; off; off >>= 1) {
        ps += __shfl_down(ps, off);
        pn += __shfl_down(pn, off);
    }
    __shared__ float ss[4], sn[4];
    const int lane = threadIdx.x & 63, w = threadIdx.x >> 6;
    if (lane == 0) { ss[w] = ps; sn[w] = pn; }
    __syncthreads();
    if (threadIdx.x == 0) {
        es[i] = ss[0] + ss[1] + ss[2] + ss[3];
        en[i] = sn[0] + sn[1] + sn[2] + sn[3];
    }
}

// ================= tmat[512][16] = h1^T @ h4 =================
__global__ __launch_bounds__(256)
void ata_kernel(const float* __restrict__ h1, const float* __restrict__ h4,
                float* __restrict__ tmat)
{
    const int r = blockIdx.x;
    float acc[16];
    #pragma unroll
    for (int c = 0; c < 16; ++c) acc[c] = 0.f;
    for (int n = threadIdx.x; n < NROW; n += 256) {
        const float hv = h1[(size_t)n * 512 + r];
        const float* h4r = h4 + (size_t)n * 16;
        #pragma unroll
        for (int c = 0; c < 16; ++c) acc[c] += hv * h4r[c];
    }
    #pragma unroll
    for (int c = 0; c < 16; ++c)
        #pragma unroll
        for (int off = 32; off; off >>= 1) acc[c] += __shfl_down(acc[c], off);
    __shared__ float red[4][16];
    const int lane = threadIdx.x & 63, w = threadIdx.x >> 6;
    if (lane == 0)
        for (int c = 0; c < 16; ++c) red[w][c] = acc[c];
    __syncthreads();
    if (threadIdx.x < 16)
        tmat[r * 16 + threadIdx.x] = red[0][threadIdx.x] + red[1][threadIdx.x] +
                                     red[2][threadIdx.x] + red[3][threadIdx.x];
}

// ================= row L2 normalize =================
__global__ __launch_bounds__(64)
void norm_kernel(const float* __restrict__ z1, float* __restrict__ out)
{
    const int i = blockIdx.x;
    const int lane = threadIdx.x;
    const float v = (lane < 16) ? z1[(size_t)i * 16 + lane] : 0.f;
    float sq = v * v;
    #pragma unroll
    for (int off = 32; off; off >>= 1) sq += __shfl_down(sq, off);
    const float tot = __shfl(sq, 0);
    const float inv = 1.0f / fmaxf(sqrtf(tot), 1e-12f);
    if (lane < 16) out[(size_t)i * 16 + lane] = v * inv;
}

extern "C" void kernel_launch(void* const* d_in, const int* in_sizes, int n_in,
                              void* d_out, int out_size, void* d_ws, size_t ws_size,
                              hipStream_t stream)
{
    const float* x    = (const float*)d_in[0];
    const float* adj  = (const float*)d_in[1];
    const float* Mm   = (const float*)d_in[2];
    const float* enc1 = (const float*)d_in[3];
    const float* enc2 = (const float*)d_in[4];
    const float* emb  = (const float*)d_in[5];
    const float* W1  = (const float*)d_in[6];
    const float* as1 = (const float*)d_in[7];
    const float* an1 = (const float*)d_in[8];
    const float* W2  = (const float*)d_in[9];
    const float* as2 = (const float*)d_in[10];
    const float* an2 = (const float*)d_in[11];
    const float* W3  = (const float*)d_in[12];
    const float* as3 = (const float*)d_in[13];
    const float* an3 = (const float*)d_in[14];
    const float* W4  = (const float*)d_in[15];
    const float* as4 = (const float*)d_in[16];
    const float* an4 = (const float*)d_in[17];
    float* out = (float*)d_out;
    (void)in_sizes; (void)n_in; (void)out_size;

    char* ws = (char*)d_ws;
    size_t off = 0;
    auto alloc = [&](size_t bytes) { char* p = ws + off; off += (bytes + 255) & ~(size_t)255; return p; };

    ushort* attnb  = (ushort*)alloc((size_t)NROW * NROW * 2);   // 33.5 MB (also hosts xb)
    ushort* Mmaskb = (ushort*)alloc((size_t)NROW * NROW * 2);   // 33.5 MB
    float*  hW     = (float*) alloc((size_t)NROW * 512 * 4);    // 8.4 MB
    ushort* hWT    = (ushort*)alloc((size_t)512 * NROW * 2);    // 4.2 MB
    float*  h1     = (float*) alloc((size_t)NROW * 512 * 4);    // 8.4 MB
    ushort* inb    = (ushort*)alloc((size_t)NROW * 512 * 2);    // 4.2 MB
    float*  h4     = (float*) alloc((size_t)NROW * 16 * 4);
    ushort* W1t    = (ushort*)alloc((size_t)512 * 1024 * 2);
    ushort* W2t    = (ushort*)alloc((size_t)256 * 512 * 2);
    ushort* W3t    = (ushort*)alloc((size_t)64 * 256 * 2);
    ushort* W4t    = (ushort*)alloc((size_t)16 * 64 * 2);
    float*  es     = (float*) alloc(NROW * 4);
    float*  en     = (float*) alloc(NROW * 4);
    float*  tmat   = (float*) alloc(512 * 16 * 4);
    float*  z1     = (float*) alloc((size_t)NROW * 16 * 4);
    const size_t pbig = (size_t)3 * NROW * 512 * 4;             // 25.2 MB
    const size_t psml = (size_t)1 * NROW * 512 * 4;             // 8.4 MB
    const bool bigws = ws_size >= off + pbig + (4u << 20);
    float* Pbuf = (float*)alloc(bigws ? pbig : psml);
    ushort* xb = attnb;   // alias: xb dead before attnb written

    auto grid_for = [&](int n4) { int g = (n4 + 255) / 256; return g > 2048 ? 2048 : g; };

    // gemm without epilogue reduce (used when finish_layer handles partials)
    auto gemm_nr = [&](const ushort* A, const ushort* Bt, float* C,
                       int M, int N, int K, int splits) {
        const int Ks = K / splits;
        if (N >= 128) {
            dim3 grid(N / 128, M / 128, splits);
            gemm_bf16<4><<<grid, 256, 0, stream>>>(A, Bt, C, Pbuf, M, N, K, Ks);
        } else {
            dim3 grid(1, M / 128, splits);
            gemm_bf16<2><<<grid, 256, 0, stream>>>(A, Bt, C, Pbuf, M, N, K, Ks);
        }
    };
    auto gemmb = [&](const ushort* A, const ushort* Bt, float* C,
                     int M, int N, int K, int splits) {
        gemm_nr(A, Bt, C, M, N, K, splits);
        if (splits > 1) {
            const int n4 = M * N / 4;
            reduce_k<<<grid_for(n4), 256, 0, stream>>>((float4*)C, (const float4*)Pbuf,
                                                       splits - 1, n4);
        }
    };
    auto trans = [&](const float* in, ushort* o, int R, int C) {
        dim3 grid((C + 31) / 32, (R + 31) / 32);
        transpose_bf16<<<grid, 256, 0, stream>>>(in, o, R, C);
    };

    const int s_att1 = bigws ? 4 : 2;
    const int s_inW2 = bigws ? 4 : 2;
    const int s_att2 = bigws ? 4 : 2;

    // ---- one-time prep
    conv_bf16<<<2048, 256, 0, stream>>>((const float4*)x, (ushort4*)xb, NROW * 1024 / 4);
    trans(W1, W1t, 1024, 512);
    trans(W2, W2t, 512, 256);
    trans(W3, W3t, 256, 64);
    trans(W4, W4t, 64, 16);

    // ---- layer 1: [4096,1024] -> [4096,512]
    gemmb(xb, W1t, hW, NROW, 512, 1024, 2);
    scores_kernel<<<NROW, 256, 0, stream>>>(hW, as1, an1, es, en, 512);
    trans(hW, hWT, NROW, 512);
    attn_build<<<NROW, 256, 0, stream>>>((const float4*)adj, (const float4*)Mm,
                                         (ushort4*)Mmaskb, (const ushort4*)nullptr,
                                         es, en, attnb);
    gemm_nr(attnb, hWT, hW, NROW, 512, NROW, s_att1);
    finish_layer<<<grid_for(NROW*512/4), 256, 0, stream>>>(
        (const float4*)hW, (const float4*)Pbuf, s_att1 - 1, NROW * 512 / 4,
        (const float4*)enc1, (ushort4*)inb, (float4*)h1);

    // ---- layer 2: [4096,512] -> [4096,256]
    gemmb(inb, W2t, hW, NROW, 256, 512, s_inW2);
    scores_kernel<<<NROW, 256, 0, stream>>>(hW, as2, an2, es, en, 256);
    trans(hW, hWT, NROW, 256);
    attn_build<<<NROW, 256, 0, stream>>>((const float4*)nullptr, (const float4*)nullptr,
                                         (ushort4*)nullptr, (const ushort4*)Mmaskb,
                                         es, en, attnb);
    gemm_nr(attnb, hWT, hW, NROW, 256, NROW, s_att2);
    finish_layer<<<grid_for(NROW*256/4), 256, 0, stream>>>(
        (const float4*)hW, (const float4*)Pbuf, s_att2 - 1, NROW * 256 / 4,
        (const float4*)enc2, (ushort4*)inb, (float4*)nullptr);

    // ---- layer 3: [4096,256] -> [4096,64]
    gemmb(inb, W3t, hW, NROW, 64, 256, 4);
    scores_kernel<<<NROW, 256, 0, stream>>>(hW, as3, an3, es, en, 64);
    trans(hW, hWT, NROW, 64);
    attn_build<<<NROW, 256, 0, stream>>>((const float4*)nullptr, (const float4*)nullptr,
                                         (ushort4*)nullptr, (const ushort4*)Mmaskb,
                                         es, en, attnb);
    gemm_nr(attnb, hWT, hW, NROW, 64, NROW, 8);
    finish_layer<<<grid_for(NROW*64/4), 256, 0, stream>>>(
        (const float4*)hW, (const float4*)Pbuf, 7, NROW * 64 / 4,
        (const float4*)emb, (ushort4*)inb, (float4*)nullptr);

    // ---- layer 4: [4096,64] -> [4096,16]
    gemmb(inb, W4t, hW, NROW, 16, 64, 1);
    scores_kernel<<<NROW, 256, 0, stream>>>(hW, as4, an4, es, en, 16);
    trans(hW, hWT, NROW, 16);
    attn_build<<<NROW, 256, 0, stream>>>((const float4*)nullptr, (const float4*)nullptr,
                                         (ushort4*)nullptr, (const ushort4*)Mmaskb,
                                         es, en, attnb);
    gemm_nr(attnb, hWT, hW, NROW, 16, NROW, 8);
    finish_layer<<<grid_for(NROW*16/4), 256, 0, stream>>>(
        (const float4*)hW, (const float4*)Pbuf, 7, NROW * 16 / 4,
        (const float4*)nullptr, (ushort4*)nullptr, (float4*)h4);

    // ---- z1 = h1 @ (h1^T @ h4); z = rownorm(z1)
    ata_kernel<<<512, 256, 0, stream>>>(h1, h4, tmat);
    {
        dim3 grid((16 + 63) / 64, NROW / 64);
        gemm_f32<<<grid, 256, 0, stream>>>(h1, tmat, z1, NROW, 16, 512);
    }
    norm_kernel<<<NROW, 64, 0, stream>>>(z1, out);
}